// Round 9
// baseline (266.973 us; speedup 1.0000x reference)
//
#include <hip/hip_runtime.h>
#include <hip/hip_bf16.h>
#include <math.h>

// Model constants (fixed by shapes)
#define NEDGE 240
#define NBAT  8
#define MROWS 1920   // NBAT*NEDGE
#define NPTS  256
#define CIN   5

typedef __attribute__((ext_vector_type(8))) short  bf16x8;
typedef __attribute__((ext_vector_type(4))) float  f32x4;

// tanh-form GELU via sigmoid: gelu(x) ~= x * sigmoid(1.5957691*x + 0.07135481*x^3)
__device__ __forceinline__ float gelu_f(float x){
    float x2 = x*x;
    float t  = fmaf(0.07135481f, x2, 1.59576912f);
    float s  = fminf(x*t, 80.f);
    float e  = __expf(s);
    float r  = __builtin_amdgcn_rcpf(e + 1.0f);
    return x*e*r;
}
__device__ __forceinline__ float wave_sum(float v){
    #pragma unroll
    for (int off=32; off>0; off>>=1) v += __shfl_xor(v, off);
    return v;
}
// wave-uniform broadcast of lane l (compile-time l) -> v_readlane
__device__ __forceinline__ float bcast(float v, int l){
    return __int_as_float(__builtin_amdgcn_readlane(__float_as_int(v), l));
}
__device__ __forceinline__ unsigned short f2bf(float x){   // RNE f32->bf16
    unsigned int u = __float_as_uint(x);
    return (unsigned short)((u + 0x7FFFu + ((u>>16)&1u)) >> 16);
}
__device__ __forceinline__ unsigned pack_bf2(float lo, float hi){
    __hip_bfloat162 t = __float22bfloat162_rn(make_float2(lo, hi));
    union { __hip_bfloat162 b; unsigned u; } cv; cv.b = t;
    return cv.u;
}

// ---------------- K0: pre-convert conv weights to bf16 MFMA A-fragments ----
__global__ __launch_bounds__(256) void k_wprep(
    const float* __restrict__ conv_w, unsigned short* __restrict__ wf)
{
    int t = blockIdx.x*256 + threadIdx.x;
    if (t >= 120*64) return;
    int lane = t & 63, f = t >> 6;
    int q = f & 1, tap = (f>>1)%3, ob = (f/6)&3, layer = f/24;
    int o = 16*ob + (lane&15);
    int ibase = 32*q + 8*(lane>>4);
    #pragma unroll
    for (int e=0;e<8;++e){
        int i = ibase + e;
        float w = conv_w[(((size_t)layer*64 + o)*64 + i)*3 + tap];
        wf[(size_t)t*8 + e] = f2bf(w);
    }
}

// ---------------- K1: stem + 5 residual conv/GN/GELU blocks + mean pool ----
// EXACT R5 structure (proven 166us). one block (512 thr) per edge;
// hbf[258][64] bf16 swizzled; wave w: o-block wb=w&3 x 128 cols.
// A-frags (6/layer) in regs, reloaded per layer under the epilogue.
__global__ __launch_bounds__(512, 2) void k_extract(
    const float* __restrict__ edge_data, const float* __restrict__ stem_w,
    const float* __restrict__ stem_b, const unsigned short* __restrict__ wf,
    const float* __restrict__ gn_g, const float* __restrict__ gn_b,
    float* __restrict__ emb0)
{
    __shared__ unsigned short hbf[258*64];    // 33024 B
    __shared__ float redg[8][2][2];           // [wave][half][{sum,sumsq}]
    __shared__ float redp[8][16];
    __shared__ float gnp[640];                // gn_g (320) ++ gn_b (320)
    const int m = blockIdx.x, tid = threadIdx.x;
    const int w = tid>>6, lane = tid&63;
    const int g = (lane>>4)&3, l15 = lane&15;
    const int wb = w&3, colbase = 128*(w>>2);
    const bf16x8* wfp = (const bf16x8*)wf;

    // A-frags for layer 0 (issue early; land during stem)
    bf16x8 A[6];
    #pragma unroll
    for (int fq=0; fq<6; ++fq)
        A[fq] = wfp[(size_t)(wb*6 + fq)*64 + lane];

    for (int i=tid; i<640; i+=512) gnp[i] = (i<320) ? gn_g[i] : gn_b[i-320];

    // ---- loop-invariant LDS addresses
    const int i0 = 16*wb + 4*g;
    unsigned raddr[3][2];
    {
        unsigned clb = (unsigned)((colbase + l15)*128);
        #pragma unroll
        for (int tap=0;tap<3;++tap)
            #pragma unroll
            for (int q=0;q<2;++q)
                raddr[tap][q] = clb + (unsigned)(((4*q+g) ^ ((l15+tap)&7))<<4);
    }
    const unsigned wb0 = (unsigned)((colbase + l15 + 1)*128
                       + (((i0>>3) ^ ((l15+1)&7))<<4) + ((i0&7)<<1));

    float h[8][4];   // [nbl][j] f32 master

    // ---- stem
    {
        const float* xs = edge_data + (size_t)m*CIN*NPTS;
        float sw[4][6];
        #pragma unroll
        for (int j=0;j<4;++j){
            int o = i0 + j;
            #pragma unroll
            for (int c=0;c<5;++c) sw[j][c] = stem_w[c*64+o];
            sw[j][5] = stem_b[o];
        }
        #pragma unroll
        for (int nbl=0;nbl<8;++nbl){
            int n = colbase + 16*nbl + l15;
            float x0=xs[n], x1=xs[NPTS+n], x2=xs[2*NPTS+n],
                  x3=xs[3*NPTS+n], x4=xs[4*NPTS+n];
            #pragma unroll
            for (int j=0;j<4;++j)
                h[nbl][j] = sw[j][5] + x0*sw[j][0] + x1*sw[j][1]
                          + x2*sw[j][2] + x3*sw[j][3] + x4*sw[j][4];
            unsigned long long pk = (unsigned long long)pack_bf2(h[nbl][0], h[nbl][1])
                                  | ((unsigned long long)pack_bf2(h[nbl][2], h[nbl][3]) << 32);
            *(unsigned long long*)((char*)hbf + wb0 + 2048*nbl) = pk;
        }
    }
    // zero halo rows n'=0 and n'=257
    if (tid < 32)       ((unsigned int*)hbf)[tid] = 0u;
    else if (tid < 64)  ((unsigned int*)hbf)[257*32 + tid - 32] = 0u;
    __syncthreads();

    // ---- 5 residual conv blocks (MFMA)
    #pragma unroll 1
    for (int layer=0; layer<5; ++layer){
        f32x4 acc[8];
        #pragma unroll
        for (int nbl=0;nbl<8;++nbl) acc[nbl] = (f32x4){0.f,0.f,0.f,0.f};

        #pragma unroll
        for (int tap=0; tap<3; ++tap)
        #pragma unroll
        for (int q=0; q<2; ++q){
            #pragma unroll
            for (int nbl=0;nbl<8;++nbl){
                bf16x8 Bv = *(const bf16x8*)((const char*)hbf
                              + raddr[tap][q] + (2048*nbl + 128*tap));
                acc[nbl] = __builtin_amdgcn_mfma_f32_16x16x32_bf16(
                               A[tap*2+q], Bv, acc[nbl], 0,0,0);
            }
        }

        // GroupNorm stats: thread's 32 values all in group 2*wb + (g>>1)
        float s=0.f, sq=0.f;
        #pragma unroll
        for (int nbl=0;nbl<8;++nbl)
            #pragma unroll
            for (int j=0;j<4;++j){ float v=acc[nbl][j]; s+=v; sq+=v*v; }
        #pragma unroll
        for (int off=1; off<=16; off<<=1){
            s  += __shfl_xor(s,  off);
            sq += __shfl_xor(sq, off);
        }
        if ((lane&31)==0){
            redg[w][lane>>5][0] = s;
            redg[w][lane>>5][1] = sq;
        }
        __syncthreads();   // #1: MFMA reads of hbf done; redg published

        // reload A with next layer's frags (regs dead; lands under epilogue)
        if (layer < 4){
            #pragma unroll
            for (int fq=0; fq<6; ++fq)
                A[fq] = wfp[(size_t)((layer+1)*24 + wb*6 + fq)*64 + lane];
        }

        int hf = g>>1;
        float S = redg[wb][hf][0] + redg[wb+4][hf][0];
        float Q = redg[wb][hf][1] + redg[wb+4][hf][1];
        float mu = S*(1.f/2048.f);
        float rstd = rsqrtf(Q*(1.f/2048.f) - mu*mu + 1e-5f);

        // GN folded to 1 FMA per value: xn = acc*K1[j] + K2[j]
        float K1[4], K2[4];
        #pragma unroll
        for (int j=0;j<4;++j){
            float gg = gnp[layer*64 + i0 + j], bb = gnp[320 + layer*64 + i0 + j];
            K1[j] = rstd*gg;
            K2[j] = fmaf(-mu, K1[j], bb);
        }
        #pragma unroll
        for (int nbl=0;nbl<8;++nbl)
            #pragma unroll
            for (int j=0;j<4;++j){
                float xn = fmaf(acc[nbl][j], K1[j], K2[j]);
                h[nbl][j] += gelu_f(xn);
            }
        if (layer < 4){
            #pragma unroll
            for (int nbl=0;nbl<8;++nbl){
                unsigned long long pk = (unsigned long long)pack_bf2(h[nbl][0], h[nbl][1])
                                      | ((unsigned long long)pack_bf2(h[nbl][2], h[nbl][3]) << 32);
                *(unsigned long long*)((char*)hbf + wb0 + 2048*nbl) = pk;
            }
            __syncthreads();   // #2: hbf ready for next layer
        }
    }

    // ---- mean pool over N (h in registers)
    float p[4];
    #pragma unroll
    for (int j=0;j<4;++j){
        float a = 0.f;
        #pragma unroll
        for (int nbl=0;nbl<8;++nbl) a += h[nbl][j];
        p[j] = a;
    }
    #pragma unroll
    for (int off=1; off<=8; off<<=1)
        #pragma unroll
        for (int j=0;j<4;++j) p[j] += __shfl_xor(p[j], off);
    if (l15==0){
        #pragma unroll
        for (int j=0;j<4;++j) redp[w][4*g+j] = p[j];
    }
    __syncthreads();
    if (tid < 64){
        int ob = tid>>4, r = tid&15;
        emb0[(size_t)m*64+tid] = (redp[ob][r] + redp[ob+4][r]) * (1.0f/256.0f);
    }
}

// ---------------- K2: merge+LN+gelu+qkv — 1-wave block, 4 rows/wave ---------
// Each weight load feeds 4 FMAs (one per row): 4x less VMEM than 1-row/wave.
__global__ __launch_bounds__(64) void k_mergeqkv(
    const float* __restrict__ emb0, const int* __restrict__ edge_types,
    const float* __restrict__ type_emb, const float* __restrict__ em_w,
    const float* __restrict__ em_b, const float* __restrict__ em_g,
    const float* __restrict__ em_bt, const float* __restrict__ wqkv,
    const float* __restrict__ bqkv, float* __restrict__ emb,
    float* __restrict__ qkv)
{
    int m0 = blockIdx.x*4;
    int ln = threadIdx.x & 63;
    float a[4], tb[4];
    #pragma unroll
    for (int r=0;r<4;++r){
        a[r]  = emb0[(size_t)(m0+r)*64+ln];
        tb[r] = type_emb[edge_types[m0+r]*64+ln];
    }
    float v[4] = {0.f,0.f,0.f,0.f};
    #pragma unroll
    for (int j=0;j<64;++j){
        float w0 = em_w[j*64+ln];
        #pragma unroll
        for (int r=0;r<4;++r) v[r] += bcast(a[r],j)*w0;
    }
    #pragma unroll
    for (int j=0;j<64;++j){
        float w1 = em_w[(64+j)*64+ln];
        #pragma unroll
        for (int r=0;r<4;++r) v[r] += bcast(tb[r],j)*w1;
    }
    float eb = em_b[ln], eg = em_g[ln], ebt = em_bt[ln];
    float e[4];
    #pragma unroll
    for (int r=0;r<4;++r){
        float x = v[r] + eb;
        float mu  = wave_sum(x)*(1.f/64.f);
        float d   = x - mu;
        float var = wave_sum(d*d)*(1.f/64.f);
        e[r] = gelu_f(d*rsqrtf(var+1e-5f)*eg + ebt);
        emb[(size_t)(m0+r)*64+ln] = e[r];
    }
    float q[4], k[4], vv[4];
    float bq = bqkv[ln], bk = bqkv[64+ln], bv = bqkv[128+ln];
    #pragma unroll
    for (int r=0;r<4;++r){ q[r]=bq; k[r]=bk; vv[r]=bv; }
    #pragma unroll
    for (int j=0;j<64;++j){
        float wq = wqkv[j*192+ln], wk = wqkv[j*192+64+ln], wv = wqkv[j*192+128+ln];
        #pragma unroll
        for (int r=0;r<4;++r){
            float ej = bcast(e[r],j);
            q[r]  += ej*wq; k[r] += ej*wk; vv[r] += ej*wv;
        }
    }
    #pragma unroll
    for (int r=0;r<4;++r){
        size_t base = (size_t)(m0+r)*192;
        qkv[base+ln]=q[r]; qkv[base+64+ln]=k[r]; qkv[base+128+ln]=vv[r];
    }
}

// ---------------- K3: attention; block = (batch, head, qtile of 64) ---------
__global__ __launch_bounds__(256) void k_attn(
    const float* __restrict__ qkv, float* __restrict__ o)
{
    __shared__ float KsT[16][244], VsT[16][244];
    int blk = blockIdx.x;
    int b  = blk >> 4;
    int h  = (blk >> 2) & 3;
    int qt = blk & 3;
    int tid = threadIdx.x;
    for (int i=tid; i<NEDGE*16; i+=256){
        int r = i>>4, d = i&15;
        size_t base = ((size_t)(b*NEDGE+r))*192 + h*16 + d;
        KsT[d][r] = qkv[base+64];
        VsT[d][r] = qkv[base+128];
    }
    __syncthreads();
    int c = tid & 3, qi = tid >> 2;
    int q = qt*64 + qi;
    bool act = (q < NEDGE);
    float qv[16];
    size_t qb = ((size_t)(b*NEDGE + (act ? q : 0)))*192 + h*16;
    #pragma unroll
    for (int d=0; d<16; ++d) qv[d] = qkv[qb+d];
    float mx = -3e38f, l = 0.f, acc[16];
    #pragma unroll
    for (int d=0; d<16; ++d) acc[d]=0.f;
    for (int k=0; k<60; ++k){
        int key = 60*c + k;
        float s=0.f;
        #pragma unroll
        for (int d=0; d<16; ++d) s += qv[d]*KsT[d][key];
        s *= 0.25f;
        if (s > mx){
            float so = __expf(mx - s);
            l *= so;
            #pragma unroll
            for (int d=0; d<16; ++d) acc[d] *= so;
            mx = s;
        }
        float pp = __expf(s - mx);
        l += pp;
        #pragma unroll
        for (int d=0; d<16; ++d) acc[d] = fmaf(pp, VsT[d][key], acc[d]);
    }
    #pragma unroll
    for (int off=1; off<=2; off<<=1){
        float mo = __shfl_xor(mx, off);
        float lo = __shfl_xor(l,  off);
        float M  = fmaxf(mx, mo);
        float ss = __expf(mx - M);
        float so = __expf(mo - M);
        l = l*ss + lo*so;
        #pragma unroll
        for (int d=0; d<16; ++d)
            acc[d] = acc[d]*ss + __shfl_xor(acc[d], off)*so;
        mx = M;
    }
    if (act && c==0){
        float inv = 1.f/l;
        size_t obase = ((size_t)(b*NEDGE+q))*64 + h*16;
        #pragma unroll
        for (int d=0; d<16; ++d) o[obase+d] = acc[d]*inv;
    }
}

// ---------------- K4: out-proj+LN1+FFN+LN2 (+ qkv | edge head) --------------
// 1-wave block, 4 rows/wave: every weight load feeds 4 FMAs.
__global__ __launch_bounds__(64) void k_postattn(
    const float* __restrict__ o, const float* __restrict__ wo,
    const float* __restrict__ bo, const float* __restrict__ g1,
    const float* __restrict__ b1ln, const float* __restrict__ w1,
    const float* __restrict__ b1, const float* __restrict__ w2,
    const float* __restrict__ b2, const float* __restrict__ g2,
    const float* __restrict__ b2ln, float* __restrict__ emb,
    const float* __restrict__ wqkv, const float* __restrict__ bqkv,
    float* __restrict__ qkv, const float* __restrict__ eh_w,
    const float* __restrict__ eh_b, float* __restrict__ eout)
{
    int m0 = blockIdx.x*4;
    int ln = threadIdx.x & 63;
    float ov[4], rr[4];
    float bo_ = bo[ln];
    #pragma unroll
    for (int r=0;r<4;++r){ ov[r] = o[(size_t)(m0+r)*64+ln]; rr[r] = bo_; }
    #pragma unroll
    for (int j=0;j<64;++j){
        float w = wo[j*64+ln];
        #pragma unroll
        for (int r=0;r<4;++r) rr[r] += bcast(ov[r],j)*w;
    }
    float g1_=g1[ln], b1_=b1ln[ln];
    float e1[4];
    #pragma unroll
    for (int r=0;r<4;++r){
        float x = emb[(size_t)(m0+r)*64+ln] + rr[r];
        float mu  = wave_sum(x)*(1.f/64.f);
        float d   = x-mu;
        float var = wave_sum(d*d)*(1.f/64.f);
        e1[r] = d*rsqrtf(var+1e-5f)*g1_ + b1_;
    }
    // FFN up: lane owns hidden units ln*4..+4, all 4 rows
    float4 bv4 = *(const float4*)(b1 + ln*4);
    float h[4][4];
    #pragma unroll
    for (int r=0;r<4;++r){ h[r][0]=bv4.x; h[r][1]=bv4.y; h[r][2]=bv4.z; h[r][3]=bv4.w; }
    #pragma unroll
    for (int j=0;j<64;++j){
        float4 wv = *(const float4*)(w1 + j*256 + ln*4);
        #pragma unroll
        for (int r=0;r<4;++r){
            float ej = bcast(e1[r],j);
            h[r][0] += ej*wv.x; h[r][1] += ej*wv.y;
            h[r][2] += ej*wv.z; h[r][3] += ej*wv.w;
        }
    }
    #pragma unroll
    for (int r=0;r<4;++r)
        #pragma unroll
        for (int u=0;u<4;++u) h[r][u] = gelu_f(h[r][u]);
    // FFN down
    float f[4];
    float b2_ = b2[ln];
    #pragma unroll
    for (int r=0;r<4;++r) f[r] = b2_;
    #pragma unroll
    for (int j=0;j<64;++j){
        #pragma unroll
        for (int u=0;u<4;++u){
            float w = w2[(j*4+u)*64+ln];
            #pragma unroll
            for (int r=0;r<4;++r) f[r] += bcast(h[r][u],j)*w;
        }
    }
    float g2_=g2[ln], b2l_=b2ln[ln];
    float e2[4];
    #pragma unroll
    for (int r=0;r<4;++r){
        float x2 = e1[r] + f[r];
        float mu2  = wave_sum(x2)*(1.f/64.f);
        float d2   = x2-mu2;
        float var2 = wave_sum(d2*d2)*(1.f/64.f);
        e2[r] = d2*rsqrtf(var2+1e-5f)*g2_ + b2l_;
        emb[(size_t)(m0+r)*64+ln] = e2[r];
    }
    if (wqkv){
        float q[4], k[4], vv[4];
        float bq = bqkv[ln], bk = bqkv[64+ln], bv = bqkv[128+ln];
        #pragma unroll
        for (int r=0;r<4;++r){ q[r]=bq; k[r]=bk; vv[r]=bv; }
        #pragma unroll
        for (int j=0;j<64;++j){
            float wq = wqkv[j*192+ln], wk = wqkv[j*192+64+ln], wv = wqkv[j*192+128+ln];
            #pragma unroll
            for (int r=0;r<4;++r){
                float ej = bcast(e2[r],j);
                q[r] += ej*wq; k[r] += ej*wk; vv[r] += ej*wv;
            }
        }
        #pragma unroll
        for (int r=0;r<4;++r){
            size_t base = (size_t)(m0+r)*192;
            qkv[base+ln]=q[r]; qkv[base+64+ln]=k[r]; qkv[base+128+ln]=vv[r];
        }
    }
    if (eh_w){   // fused edge head (layer 1)
        float w0 = eh_w[ln*2+0], w1e = eh_w[ln*2+1];
        #pragma unroll
        for (int r=0;r<4;++r){
            float p0 = wave_sum(e2[r]*w0);
            float p1 = wave_sum(e2[r]*w1e);
            if (ln==0){
                eout[(size_t)(m0+r)*2+0] = p0 + eh_b[0];
                eout[(size_t)(m0+r)*2+1] = p1 + eh_b[1];
            }
        }
    }
}

// ---------------- K5: node head ---------------------------------------------
__global__ __launch_bounds__(256) void k_nodehead(
    const float* __restrict__ emb, const float* __restrict__ nm_w,
    const float* __restrict__ nm_b, const float* __restrict__ nm_g,
    const float* __restrict__ nm_bt, const float* __restrict__ nh_w,
    const float* __restrict__ nh_b, const int* __restrict__ pp,
    const int* __restrict__ xp, const int* __restrict__ yp,
    float* __restrict__ out)
{
    int wid = blockIdx.x*4 + (threadIdx.x>>6);
    int ln  = threadIdx.x & 63;
    int p = pp[0], xi = xp[0], yi = yp[0];
    int nu = p-2;
    if (wid >= NBAT*nu) return;
    int b = wid / nu, r = wid % nu;
    int u=-1, cnt=0;
    for (int i=0;i<p;++i){ if (i!=xi && i!=yi){ if (cnt==r){u=i;break;} ++cnt; } }
    #define EIDX(a,v) ((a)*(p-1) + (v) - (((v)>(a))?1:0))
    int iux = EIDX(u,xi), iuy = EIDX(u,yi), ixu = EIDX(xi,u), iyu = EIDX(yi,u);
    float g0 = emb[((size_t)(b*NEDGE+iux))*64+ln];
    float g1 = emb[((size_t)(b*NEDGE+iuy))*64+ln];
    float g2 = emb[((size_t)(b*NEDGE+ixu))*64+ln];
    float g3 = emb[((size_t)(b*NEDGE+iyu))*64+ln];
    float v = nm_b[ln];
    #pragma unroll
    for (int j=0;j<64;++j) v += bcast(g0,j)*nm_w[j*64+ln];
    #pragma unroll
    for (int j=0;j<64;++j) v += bcast(g1,j)*nm_w[(64+j)*64+ln];
    #pragma unroll
    for (int j=0;j<64;++j) v += bcast(g2,j)*nm_w[(128+j)*64+ln];
    #pragma unroll
    for (int j=0;j<64;++j) v += bcast(g3,j)*nm_w[(192+j)*64+ln];
    float mu  = wave_sum(v)*(1.f/64.f);
    float d   = v-mu;
    float var = wave_sum(d*d)*(1.f/64.f);
    float node = gelu_f(d*rsqrtf(var+1e-5f)*nm_g[ln] + nm_bt[ln]);
    float pl[8];
    #pragma unroll
    for (int c=0;c<8;++c) pl[c] = node*nh_w[ln*8+c];
    #pragma unroll
    for (int off=32; off>0; off>>=1)
        #pragma unroll
        for (int c=0;c<8;++c) pl[c] += __shfl_xor(pl[c], off);
    if (ln==0){
        #pragma unroll
        for (int c=0;c<8;++c) out[MROWS*2 + ((size_t)wid)*8 + c] = pl[c] + nh_b[c];
    }
}

extern "C" void kernel_launch(void* const* d_in, const int* in_sizes, int n_in,
                              void* d_out, int out_size, void* d_ws, size_t ws_size,
                              hipStream_t stream)
{
    const float* edge_data = (const float*)d_in[0];
    const int*   edge_types= (const int*)d_in[1];
    const int* pp = (const int*)d_in[3];
    const int* xp = (const int*)d_in[4];
    const int* yp = (const int*)d_in[5];
    const float* stem_w=(const float*)d_in[6];
    const float* stem_b=(const float*)d_in[7];
    const float* conv_w=(const float*)d_in[8];
    const float* gn_g=(const float*)d_in[9];
    const float* gn_b=(const float*)d_in[10];
    const float* type_emb=(const float*)d_in[11];
    const float* em_w=(const float*)d_in[12];
    const float* em_b=(const float*)d_in[13];
    const float* em_g=(const float*)d_in[14];
    const float* em_bt=(const float*)d_in[15];
    const float* a_wqkv=(const float*)d_in[16];
    const float* a_bqkv=(const float*)d_in[17];
    const float* a_wo=(const float*)d_in[18];
    const float* a_bo=(const float*)d_in[19];
    const float* ln1_g=(const float*)d_in[20];
    const float* ln1_b=(const float*)d_in[21];
    const float* ff_w1=(const float*)d_in[22];
    const float* ff_b1=(const float*)d_in[23];
    const float* ff_w2=(const float*)d_in[24];
    const float* ff_b2=(const float*)d_in[25];
    const float* ln2_g=(const float*)d_in[26];
    const float* ln2_b=(const float*)d_in[27];
    const float* eh_w=(const float*)d_in[28];
    const float* eh_b=(const float*)d_in[29];
    const float* nm_w=(const float*)d_in[30];
    const float* nm_b=(const float*)d_in[31];
    const float* nm_g=(const float*)d_in[32];
    const float* nm_bt=(const float*)d_in[33];
    const float* nh_w=(const float*)d_in[34];
    const float* nh_b=(const float*)d_in[35];
    (void)in_sizes; (void)n_in; (void)out_size; (void)ws_size;

    unsigned short* wfrag = (unsigned short*)d_ws;
    float* wsf  = (float*)d_ws;
    float* emb  = wsf + 30720;
    float* qkvb = emb + 122880;
    float* obuf = qkvb + 368640;
    float* outp = (float*)d_out;

    k_wprep   <<<30, 256, 0, stream>>>(conv_w, wfrag);
    k_extract <<<MROWS, 512, 0, stream>>>(edge_data, stem_w, stem_b, wfrag, gn_g, gn_b, emb);
    k_mergeqkv<<<MROWS/4, 64, 0, stream>>>(emb, edge_types, type_emb, em_w, em_b, em_g,
                                           em_bt, a_wqkv, a_bqkv, emb, qkvb);
    // layer 0
    k_attn    <<<NBAT*16, 256, 0, stream>>>(qkvb, obuf);
    k_postattn<<<MROWS/4, 64, 0, stream>>>(obuf, a_wo, a_bo, ln1_g, ln1_b,
                                           ff_w1, ff_b1, ff_w2, ff_b2, ln2_g, ln2_b,
                                           emb, a_wqkv + (size_t)64*192, a_bqkv + 192, qkvb,
                                           (const float*)nullptr, (const float*)nullptr, (float*)nullptr);
    // layer 1 (+ fused edge head)
    k_attn    <<<NBAT*16, 256, 0, stream>>>(qkvb, obuf);
    k_postattn<<<MROWS/4, 64, 0, stream>>>(obuf, a_wo + (size_t)64*64, a_bo + 64,
                                           ln1_g + 64, ln1_b + 64,
                                           ff_w1 + (size_t)64*256, ff_b1 + 256,
                                           ff_w2 + (size_t)256*64, ff_b2 + 64,
                                           ln2_g + 64, ln2_b + 64,
                                           emb, (const float*)nullptr, (const float*)nullptr, qkvb,
                                           eh_w, eh_b, outp);
    k_nodehead<<<28, 256, 0, stream>>>(emb, nm_w, nm_b, nm_g, nm_bt,
                                       nh_w, nh_b, pp, xp, yp, outp);
}

// Round 10
// 255.431 us; speedup vs baseline: 1.0452x; 1.0452x over previous
//
#include <hip/hip_runtime.h>
#include <hip/hip_bf16.h>
#include <math.h>

// Model constants (fixed by shapes)
#define NEDGE 240
#define NBAT  8
#define MROWS 1920   // NBAT*NEDGE
#define NPTS  256
#define CIN   5

typedef __attribute__((ext_vector_type(8))) short  bf16x8;
typedef __attribute__((ext_vector_type(4))) float  f32x4;

// tanh-form GELU via sigmoid: gelu(x) ~= x * sigmoid(1.5957691*x + 0.07135481*x^3)
__device__ __forceinline__ float gelu_f(float x){
    float x2 = x*x;
    float t  = fmaf(0.07135481f, x2, 1.59576912f);
    float s  = fminf(x*t, 80.f);
    float e  = __expf(s);
    float r  = __builtin_amdgcn_rcpf(e + 1.0f);
    return x*e*r;
}
__device__ __forceinline__ float wave_sum(float v){
    #pragma unroll
    for (int off=32; off>0; off>>=1) v += __shfl_xor(v, off);
    return v;
}
// wave-uniform broadcast of lane l (compile-time l) -> v_readlane
__device__ __forceinline__ float bcast(float v, int l){
    return __int_as_float(__builtin_amdgcn_readlane(__float_as_int(v), l));
}
__device__ __forceinline__ unsigned short f2bf(float x){   // RNE f32->bf16
    unsigned int u = __float_as_uint(x);
    return (unsigned short)((u + 0x7FFFu + ((u>>16)&1u)) >> 16);
}
__device__ __forceinline__ unsigned pack_bf2(float lo, float hi){
    __hip_bfloat162 t = __float22bfloat162_rn(make_float2(lo, hi));
    union { __hip_bfloat162 b; unsigned u; } cv; cv.b = t;
    return cv.u;
}
// VALU-pipe 16-lane rotate-reduce (DPP row_ror) — keeps stats off the DS pipe
#define DPP_ADD(v, ctrl) \
    { int _t = __builtin_amdgcn_update_dpp(0, __float_as_int(v), (ctrl), 0xF, 0xF, false); \
      (v) += __int_as_float(_t); }
#define ROW16_SUM(v) { DPP_ADD(v,0x121); DPP_ADD(v,0x122); DPP_ADD(v,0x124); DPP_ADD(v,0x128); }
#define SWZ_ADD(v, patt) \
    (v) += __int_as_float(__builtin_amdgcn_ds_swizzle(__float_as_int(v), (patt)))

// ---------------- K0: pre-convert conv weights to bf16 MFMA A-fragments ----
// frag id f = layer*24 + ob*6 + tap*2 + q ; lane m=lane&15 (out ch in o-block),
// k = 32q + 8*(lane>>4) + e (in ch). wf[(f*64+lane)*8+e]
__global__ __launch_bounds__(256) void k_wprep(
    const float* __restrict__ conv_w, unsigned short* __restrict__ wf)
{
    int t = blockIdx.x*256 + threadIdx.x;
    if (t >= 120*64) return;
    int lane = t & 63, f = t >> 6;
    int q = f & 1, tap = (f>>1)%3, ob = (f/6)&3, layer = f/24;
    int o = 16*ob + (lane&15);
    int ibase = 32*q + 8*(lane>>4);
    #pragma unroll
    for (int e=0;e<8;++e){
        int i = ibase + e;
        float w = conv_w[(((size_t)layer*64 + o)*64 + i)*3 + tap];
        wf[(size_t)t*8 + e] = f2bf(w);
    }
}

// ---------------- K1: stem + 5 residual conv/GN/GELU blocks + mean pool ----
// one block (512 thr) per edge; hbf[258][64] bf16, XOR-swizzled 16B chunks.
// Wave w: obgrp=w&1 (o-blocks 2*obgrp,2*obgrp+1), cols 64*(w>>1).
// Each B-frag ds_read feeds 2 MFMAs (24 reads/layer vs R5's 48).
// A-frags: current tap pair (4 regs) + next-tap prefetch issued BEFORE the
// tap's MFMAs (VMEM hides under DS+MFMA; never a blocking wait).
__global__ __launch_bounds__(512, 2) void k_extract(
    const float* __restrict__ edge_data, const float* __restrict__ stem_w,
    const float* __restrict__ stem_b, const unsigned short* __restrict__ wf,
    const float* __restrict__ gn_g, const float* __restrict__ gn_b,
    float* __restrict__ emb0)
{
    __shared__ unsigned short hbf[258*64];    // 33024 B
    __shared__ float redg[8][2][2][2];        // [wave][half][ob][{s,sq}]
    __shared__ float redp[8][4][8];           // [wave][g][ob*4+j]
    __shared__ float gnp[640];                // gn_g (320) ++ gn_b (320)
    const int m = blockIdx.x, tid = threadIdx.x;
    const int w = tid>>6, lane = tid&63;
    const int g = (lane>>4)&3, l15 = lane&15;
    const int obgrp = w&1, colbase = 64*(w>>1);
    const bf16x8* wfp = (const bf16x8*)wf;

    // A-frags layer0/tap0 (issue early; land during stem): a = ob*2+q
    bf16x8 Ac[4], An[4];
    #pragma unroll
    for (int a=0;a<4;++a)
        Ac[a] = wfp[(size_t)((2*obgrp + (a>>1))*6 + (a&1))*64 + lane];

    for (int i=tid; i<640; i+=512) gnp[i] = (i<320) ? gn_g[i] : gn_b[i-320];

    // ---- loop-invariant LDS addresses
    int i0[2];
    i0[0] = 16*(2*obgrp+0) + 4*g;
    i0[1] = 16*(2*obgrp+1) + 4*g;
    unsigned raddr[3][2];
    {
        unsigned clb = (unsigned)((colbase + l15)*128);
        #pragma unroll
        for (int tap=0;tap<3;++tap)
            #pragma unroll
            for (int q=0;q<2;++q)
                raddr[tap][q] = clb + (unsigned)(((4*q+g) ^ ((l15+tap)&7))<<4);
    }
    unsigned wbase[2];
    #pragma unroll
    for (int ob=0;ob<2;++ob)
        wbase[ob] = (unsigned)((colbase + l15 + 1)*128
                  + (((i0[ob]>>3) ^ ((l15+1)&7))<<4) + ((i0[ob]&7)<<1));

    float h[2][4][4];   // [ob][nbl][j] f32 master

    // ---- stem
    {
        const float* xs = edge_data + (size_t)m*CIN*NPTS;
        float xv[4][5];
        #pragma unroll
        for (int nbl=0;nbl<4;++nbl){
            int n = colbase + 16*nbl + l15;
            #pragma unroll
            for (int c=0;c<5;++c) xv[nbl][c] = xs[c*NPTS + n];
        }
        #pragma unroll
        for (int ob=0;ob<2;++ob){
            #pragma unroll
            for (int j=0;j<4;++j){
                int o = i0[ob] + j;
                float w0=stem_w[o], w1=stem_w[64+o], w2=stem_w[128+o],
                      w3=stem_w[192+o], w4=stem_w[256+o], sb=stem_b[o];
                #pragma unroll
                for (int nbl=0;nbl<4;++nbl)
                    h[ob][nbl][j] = sb + xv[nbl][0]*w0 + xv[nbl][1]*w1
                                  + xv[nbl][2]*w2 + xv[nbl][3]*w3 + xv[nbl][4]*w4;
            }
            #pragma unroll
            for (int nbl=0;nbl<4;++nbl){
                unsigned long long pk = (unsigned long long)pack_bf2(h[ob][nbl][0],h[ob][nbl][1])
                                      | ((unsigned long long)pack_bf2(h[ob][nbl][2],h[ob][nbl][3]) << 32);
                *(unsigned long long*)((char*)hbf + wbase[ob] + 2048*nbl) = pk;
            }
        }
    }
    // zero halo rows n'=0 and n'=257
    if (tid < 32)       ((unsigned int*)hbf)[tid] = 0u;
    else if (tid < 64)  ((unsigned int*)hbf)[257*32 + tid - 32] = 0u;
    __syncthreads();

    // ---- 5 residual conv blocks (MFMA)
    #pragma unroll 1
    for (int layer=0; layer<5; ++layer){
        f32x4 acc[2][4];   // [ob][nbl]
        #pragma unroll
        for (int ob=0;ob<2;++ob)
            #pragma unroll
            for (int nbl=0;nbl<4;++nbl) acc[ob][nbl] = (f32x4){0.f,0.f,0.f,0.f};

        #pragma unroll
        for (int tap=0; tap<3; ++tap){
            // prefetch next tap's (or next layer tap0's) A-frags
            bool doNext = (tap < 2) || (layer < 4);
            int nl = (tap < 2) ? layer : layer+1;
            int nt = (tap < 2) ? tap+1 : 0;
            if (doNext){
                #pragma unroll
                for (int a=0;a<4;++a)
                    An[a] = wfp[(size_t)(nl*24 + (2*obgrp + (a>>1))*6 + nt*2 + (a&1))*64 + lane];
            }
            #pragma unroll
            for (int q=0; q<2; ++q)
            #pragma unroll
            for (int nbl=0; nbl<4; ++nbl){
                bf16x8 Bv = *(const bf16x8*)((const char*)hbf
                              + raddr[tap][q] + (2048*nbl + 128*tap));
                #pragma unroll
                for (int ob=0; ob<2; ++ob)
                    acc[ob][nbl] = __builtin_amdgcn_mfma_f32_16x16x32_bf16(
                                       Ac[ob*2+q], Bv, acc[ob][nbl], 0,0,0);
            }
            if (doNext){
                #pragma unroll
                for (int a=0;a<4;++a) Ac[a] = An[a];
            }
        }

        // GroupNorm stats: group(ob) = 2*(2*obgrp+ob) + (g>>1)
        float s[2], sq[2];
        #pragma unroll
        for (int ob=0;ob<2;++ob){
            float a=0.f, b=0.f;
            #pragma unroll
            for (int nbl=0;nbl<4;++nbl)
                #pragma unroll
                for (int j=0;j<4;++j){ float v=acc[ob][nbl][j]; a+=v; b+=v*v; }
            s[ob]=a; sq[ob]=b;
        }
        #pragma unroll
        for (int ob=0;ob<2;++ob){ ROW16_SUM(s[ob]); ROW16_SUM(sq[ob]); }
        #pragma unroll
        for (int ob=0;ob<2;++ob){ SWZ_ADD(s[ob],0x401F); SWZ_ADD(sq[ob],0x401F); }
        if ((lane&31)==0){
            int half = lane>>5;
            #pragma unroll
            for (int ob=0;ob<2;++ob){
                redg[w][half][ob][0] = s[ob];
                redg[w][half][ob][1] = sq[ob];
            }
        }
        __syncthreads();   // #1: MFMA reads of hbf done; redg published

        int hf = g>>1;
        #pragma unroll
        for (int ob=0;ob<2;++ob){
            float S = redg[obgrp][hf][ob][0] + redg[obgrp+2][hf][ob][0]
                    + redg[obgrp+4][hf][ob][0] + redg[obgrp+6][hf][ob][0];
            float Q = redg[obgrp][hf][ob][1] + redg[obgrp+2][hf][ob][1]
                    + redg[obgrp+4][hf][ob][1] + redg[obgrp+6][hf][ob][1];
            float mu = S*(1.f/2048.f);
            float rstd = rsqrtf(Q*(1.f/2048.f) - mu*mu + 1e-5f);
            // GN folded to 1 FMA per value
            float K1[4], K2[4];
            #pragma unroll
            for (int j=0;j<4;++j){
                float gg = gnp[layer*64 + i0[ob] + j], bb = gnp[320 + layer*64 + i0[ob] + j];
                K1[j] = rstd*gg;
                K2[j] = fmaf(-mu, K1[j], bb);
            }
            #pragma unroll
            for (int nbl=0;nbl<4;++nbl)
                #pragma unroll
                for (int j=0;j<4;++j){
                    float xn = fmaf(acc[ob][nbl][j], K1[j], K2[j]);
                    h[ob][nbl][j] += gelu_f(xn);
                }
        }
        if (layer < 4){
            #pragma unroll
            for (int ob=0;ob<2;++ob)
            #pragma unroll
            for (int nbl=0;nbl<4;++nbl){
                unsigned long long pk = (unsigned long long)pack_bf2(h[ob][nbl][0],h[ob][nbl][1])
                                      | ((unsigned long long)pack_bf2(h[ob][nbl][2],h[ob][nbl][3]) << 32);
                *(unsigned long long*)((char*)hbf + wbase[ob] + 2048*nbl) = pk;
            }
            __syncthreads();   // #2: hbf ready for next layer
        }
    }

    // ---- mean pool over N
    #pragma unroll
    for (int ob=0;ob<2;++ob){
        float p[4];
        #pragma unroll
        for (int j=0;j<4;++j){
            float v = h[ob][0][j]+h[ob][1][j]+h[ob][2][j]+h[ob][3][j];
            ROW16_SUM(v);
            p[j] = v;
        }
        if (l15==0){
            #pragma unroll
            for (int j=0;j<4;++j) redp[w][g][ob*4+j] = p[j];
        }
    }
    __syncthreads();
    if (tid < 64){
        int og = tid>>5, ob = (tid>>4)&1, gg = (tid>>2)&3, j = tid&3;
        float sum = redp[og][gg][ob*4+j]   + redp[og+2][gg][ob*4+j]
                  + redp[og+4][gg][ob*4+j] + redp[og+6][gg][ob*4+j];
        emb0[(size_t)m*64+tid] = sum * (1.0f/256.0f);
    }
}

// ---------------- K2: merge+LN+gelu+qkv — 256 thr, 2 rows/wave --------------
__global__ __launch_bounds__(256) void k_mergeqkv(
    const float* __restrict__ emb0, const int* __restrict__ edge_types,
    const float* __restrict__ type_emb, const float* __restrict__ em_w,
    const float* __restrict__ em_b, const float* __restrict__ em_g,
    const float* __restrict__ em_bt, const float* __restrict__ wqkv,
    const float* __restrict__ bqkv, float* __restrict__ emb,
    float* __restrict__ qkv)
{
    int m0 = blockIdx.x*8 + (threadIdx.x>>6)*2;
    int ln = threadIdx.x & 63;
    float a[2], tb[2];
    #pragma unroll
    for (int r=0;r<2;++r){
        a[r]  = emb0[(size_t)(m0+r)*64+ln];
        tb[r] = type_emb[edge_types[m0+r]*64+ln];
    }
    float v[2] = {0.f,0.f};
    #pragma unroll
    for (int j=0;j<64;++j){
        float w0 = em_w[j*64+ln];
        v[0] += bcast(a[0],j)*w0; v[1] += bcast(a[1],j)*w0;
    }
    #pragma unroll
    for (int j=0;j<64;++j){
        float w1 = em_w[(64+j)*64+ln];
        v[0] += bcast(tb[0],j)*w1; v[1] += bcast(tb[1],j)*w1;
    }
    float eb = em_b[ln], eg = em_g[ln], ebt = em_bt[ln];
    float e[2];
    #pragma unroll
    for (int r=0;r<2;++r){
        float x = v[r] + eb;
        float mu  = wave_sum(x)*(1.f/64.f);
        float d   = x - mu;
        float var = wave_sum(d*d)*(1.f/64.f);
        e[r] = gelu_f(d*rsqrtf(var+1e-5f)*eg + ebt);
        emb[(size_t)(m0+r)*64+ln] = e[r];
    }
    float q[2], k[2], vv[2];
    float bq = bqkv[ln], bk = bqkv[64+ln], bv = bqkv[128+ln];
    #pragma unroll
    for (int r=0;r<2;++r){ q[r]=bq; k[r]=bk; vv[r]=bv; }
    #pragma unroll
    for (int j=0;j<64;++j){
        float wq = wqkv[j*192+ln], wk = wqkv[j*192+64+ln], wv = wqkv[j*192+128+ln];
        #pragma unroll
        for (int r=0;r<2;++r){
            float ej = bcast(e[r],j);
            q[r] += ej*wq; k[r] += ej*wk; vv[r] += ej*wv;
        }
    }
    #pragma unroll
    for (int r=0;r<2;++r){
        size_t base = (size_t)(m0+r)*192;
        qkv[base+ln]=q[r]; qkv[base+64+ln]=k[r]; qkv[base+128+ln]=vv[r];
    }
}

// ---------------- K3: attention; block = (batch, head, qtile of 64) ---------
__global__ __launch_bounds__(256) void k_attn(
    const float* __restrict__ qkv, float* __restrict__ o)
{
    __shared__ float KsT[16][244], VsT[16][244];
    int blk = blockIdx.x;
    int b  = blk >> 4;
    int h  = (blk >> 2) & 3;
    int qt = blk & 3;
    int tid = threadIdx.x;
    for (int i=tid; i<NEDGE*16; i+=256){
        int r = i>>4, d = i&15;
        size_t base = ((size_t)(b*NEDGE+r))*192 + h*16 + d;
        KsT[d][r] = qkv[base+64];
        VsT[d][r] = qkv[base+128];
    }
    __syncthreads();
    int c = tid & 3, qi = tid >> 2;
    int q = qt*64 + qi;
    bool act = (q < NEDGE);
    float qv[16];
    size_t qb = ((size_t)(b*NEDGE + (act ? q : 0)))*192 + h*16;
    #pragma unroll
    for (int d=0; d<16; ++d) qv[d] = qkv[qb+d];
    float mx = -3e38f, l = 0.f, acc[16];
    #pragma unroll
    for (int d=0; d<16; ++d) acc[d]=0.f;
    for (int k=0; k<60; ++k){
        int key = 60*c + k;
        float s=0.f;
        #pragma unroll
        for (int d=0; d<16; ++d) s += qv[d]*KsT[d][key];
        s *= 0.25f;
        if (s > mx){
            float so = __expf(mx - s);
            l *= so;
            #pragma unroll
            for (int d=0; d<16; ++d) acc[d] *= so;
            mx = s;
        }
        float pp = __expf(s - mx);
        l += pp;
        #pragma unroll
        for (int d=0; d<16; ++d) acc[d] = fmaf(pp, VsT[d][key], acc[d]);
    }
    #pragma unroll
    for (int off=1; off<=2; off<<=1){
        float mo = __shfl_xor(mx, off);
        float lo = __shfl_xor(l,  off);
        float M  = fmaxf(mx, mo);
        float ss = __expf(mx - M);
        float so = __expf(mo - M);
        l = l*ss + lo*so;
        #pragma unroll
        for (int d=0; d<16; ++d)
            acc[d] = acc[d]*ss + __shfl_xor(acc[d], off)*so;
        mx = M;
    }
    if (act && c==0){
        float inv = 1.f/l;
        size_t obase = ((size_t)(b*NEDGE+q))*64 + h*16;
        #pragma unroll
        for (int d=0; d<16; ++d) o[obase+d] = acc[d]*inv;
    }
}

// ---------------- K4: out-proj+LN1+FFN+LN2 (+ qkv | edge head) --------------
// 256 thr, 2 rows/wave: each weight load feeds 2 FMAs; 960 waves for TLP.
__global__ __launch_bounds__(256) void k_postattn(
    const float* __restrict__ o, const float* __restrict__ wo,
    const float* __restrict__ bo, const float* __restrict__ g1,
    const float* __restrict__ b1ln, const float* __restrict__ w1,
    const float* __restrict__ b1, const float* __restrict__ w2,
    const float* __restrict__ b2, const float* __restrict__ g2,
    const float* __restrict__ b2ln, float* __restrict__ emb,
    const float* __restrict__ wqkv, const float* __restrict__ bqkv,
    float* __restrict__ qkv, const float* __restrict__ eh_w,
    const float* __restrict__ eh_b, float* __restrict__ eout)
{
    int m0 = blockIdx.x*8 + (threadIdx.x>>6)*2;
    int ln = threadIdx.x & 63;
    float ov[2], rr[2];
    float bo_ = bo[ln];
    #pragma unroll
    for (int r=0;r<2;++r){ ov[r] = o[(size_t)(m0+r)*64+ln]; rr[r] = bo_; }
    #pragma unroll
    for (int j=0;j<64;++j){
        float w = wo[j*64+ln];
        rr[0] += bcast(ov[0],j)*w; rr[1] += bcast(ov[1],j)*w;
    }
    float g1_=g1[ln], b1_=b1ln[ln];
    float e1[2];
    #pragma unroll
    for (int r=0;r<2;++r){
        float x = emb[(size_t)(m0+r)*64+ln] + rr[r];
        float mu  = wave_sum(x)*(1.f/64.f);
        float d   = x-mu;
        float var = wave_sum(d*d)*(1.f/64.f);
        e1[r] = d*rsqrtf(var+1e-5f)*g1_ + b1_;
    }
    float4 bv4 = *(const float4*)(b1 + ln*4);
    float h[2][4];
    #pragma unroll
    for (int r=0;r<2;++r){ h[r][0]=bv4.x; h[r][1]=bv4.y; h[r][2]=bv4.z; h[r][3]=bv4.w; }
    #pragma unroll
    for (int j=0;j<64;++j){
        float4 wv = *(const float4*)(w1 + j*256 + ln*4);
        #pragma unroll
        for (int r=0;r<2;++r){
            float ej = bcast(e1[r],j);
            h[r][0] += ej*wv.x; h[r][1] += ej*wv.y;
            h[r][2] += ej*wv.z; h[r][3] += ej*wv.w;
        }
    }
    #pragma unroll
    for (int r=0;r<2;++r)
        #pragma unroll
        for (int u=0;u<4;++u) h[r][u] = gelu_f(h[r][u]);
    float f[2];
    float b2_ = b2[ln];
    f[0]=b2_; f[1]=b2_;
    #pragma unroll
    for (int j=0;j<64;++j){
        #pragma unroll
        for (int u=0;u<4;++u){
            float w = w2[(j*4+u)*64+ln];
            f[0] += bcast(h[0][u],j)*w; f[1] += bcast(h[1][u],j)*w;
        }
    }
    float g2_=g2[ln], b2l_=b2ln[ln];
    float e2[2];
    #pragma unroll
    for (int r=0;r<2;++r){
        float x2 = e1[r] + f[r];
        float mu2  = wave_sum(x2)*(1.f/64.f);
        float d2   = x2-mu2;
        float var2 = wave_sum(d2*d2)*(1.f/64.f);
        e2[r] = d2*rsqrtf(var2+1e-5f)*g2_ + b2l_;
        emb[(size_t)(m0+r)*64+ln] = e2[r];
    }
    if (wqkv){
        float q[2], k[2], vv[2];
        float bq = bqkv[ln], bk = bqkv[64+ln], bv = bqkv[128+ln];
        #pragma unroll
        for (int r=0;r<2;++r){ q[r]=bq; k[r]=bk; vv[r]=bv; }
        #pragma unroll
        for (int j=0;j<64;++j){
            float wq = wqkv[j*192+ln], wk = wqkv[j*192+64+ln], wv = wqkv[j*192+128+ln];
            #pragma unroll
            for (int r=0;r<2;++r){
                float ej = bcast(e2[r],j);
                q[r] += ej*wq; k[r] += ej*wk; vv[r] += ej*wv;
            }
        }
        #pragma unroll
        for (int r=0;r<2;++r){
            size_t base = (size_t)(m0+r)*192;
            qkv[base+ln]=q[r]; qkv[base+64+ln]=k[r]; qkv[base+128+ln]=vv[r];
        }
    }
    if (eh_w){   // fused edge head (layer 1)
        float w0 = eh_w[ln*2+0], w1e = eh_w[ln*2+1];
        #pragma unroll
        for (int r=0;r<2;++r){
            float p0 = wave_sum(e2[r]*w0);
            float p1 = wave_sum(e2[r]*w1e);
            if (ln==0){
                eout[(size_t)(m0+r)*2+0] = p0 + eh_b[0];
                eout[(size_t)(m0+r)*2+1] = p1 + eh_b[1];
            }
        }
    }
}

// ---------------- K5: node head ---------------------------------------------
__global__ __launch_bounds__(256) void k_nodehead(
    const float* __restrict__ emb, const float* __restrict__ nm_w,
    const float* __restrict__ nm_b, const float* __restrict__ nm_g,
    const float* __restrict__ nm_bt, const float* __restrict__ nh_w,
    const float* __restrict__ nh_b, const int* __restrict__ pp,
    const int* __restrict__ xp, const int* __restrict__ yp,
    float* __restrict__ out)
{
    int wid = blockIdx.x*4 + (threadIdx.x>>6);
    int ln  = threadIdx.x & 63;
    int p = pp[0], xi = xp[0], yi = yp[0];
    int nu = p-2;
    if (wid >= NBAT*nu) return;
    int b = wid / nu, r = wid % nu;
    int u=-1, cnt=0;
    for (int i=0;i<p;++i){ if (i!=xi && i!=yi){ if (cnt==r){u=i;break;} ++cnt; } }
    #define EIDX(a,v) ((a)*(p-1) + (v) - (((v)>(a))?1:0))
    int iux = EIDX(u,xi), iuy = EIDX(u,yi), ixu = EIDX(xi,u), iyu = EIDX(yi,u);
    float g0 = emb[((size_t)(b*NEDGE+iux))*64+ln];
    float g1 = emb[((size_t)(b*NEDGE+iuy))*64+ln];
    float g2 = emb[((size_t)(b*NEDGE+ixu))*64+ln];
    float g3 = emb[((size_t)(b*NEDGE+iyu))*64+ln];
    float v = nm_b[ln];
    #pragma unroll
    for (int j=0;j<64;++j) v += bcast(g0,j)*nm_w[j*64+ln];
    #pragma unroll
    for (int j=0;j<64;++j) v += bcast(g1,j)*nm_w[(64+j)*64+ln];
    #pragma unroll
    for (int j=0;j<64;++j) v += bcast(g2,j)*nm_w[(128+j)*64+ln];
    #pragma unroll
    for (int j=0;j<64;++j) v += bcast(g3,j)*nm_w[(192+j)*64+ln];
    float mu  = wave_sum(v)*(1.f/64.f);
    float d   = v-mu;
    float var = wave_sum(d*d)*(1.f/64.f);
    float node = gelu_f(d*rsqrtf(var+1e-5f)*nm_g[ln] + nm_bt[ln]);
    float pl[8];
    #pragma unroll
    for (int c=0;c<8;++c) pl[c] = node*nh_w[ln*8+c];
    #pragma unroll
    for (int off=32; off>0; off>>=1)
        #pragma unroll
        for (int c=0;c<8;++c) pl[c] += __shfl_xor(pl[c], off);
    if (ln==0){
        #pragma unroll
        for (int c=0;c<8;++c) out[MROWS*2 + ((size_t)wid)*8 + c] = pl[c] + nh_b[c];
    }
}

extern "C" void kernel_launch(void* const* d_in, const int* in_sizes, int n_in,
                              void* d_out, int out_size, void* d_ws, size_t ws_size,
                              hipStream_t stream)
{
    const float* edge_data = (const float*)d_in[0];
    const int*   edge_types= (const int*)d_in[1];
    const int* pp = (const int*)d_in[3];
    const int* xp = (const int*)d_in[4];
    const int* yp = (const int*)d_in[5];
    const float* stem_w=(const float*)d_in[6];
    const float* stem_b=(const float*)d_in[7];
    const float* conv_w=(const float*)d_in[8];
    const float* gn_g=(const float*)d_in[9];
    const float* gn_b=(const float*)d_in[10];
    const float* type_emb=(const float*)d_in[11];
    const float* em_w=(const float*)d_in[12];
    const float* em_b=(const float*)d_in[13];
    const float* em_g=(const float*)d_in[14];
    const float* em_bt=(const float*)d_in[15];
    const float* a_wqkv=(const float*)d_in[16];
    const float* a_bqkv=(const float*)d_in[17];
    const float* a_wo=(const float*)d_in[18];
    const float* a_bo=(const float*)d_in[19];
    const float* ln1_g=(const float*)d_in[20];
    const float* ln1_b=(const float*)d_in[21];
    const float* ff_w1=(const float*)d_in[22];
    const float* ff_b1=(const float*)d_in[23];
    const float* ff_w2=(const float*)d_in[24];
    const float* ff_b2=(const float*)d_in[25];
    const float* ln2_g=(const float*)d_in[26];
    const float* ln2_b=(const float*)d_in[27];
    const float* eh_w=(const float*)d_in[28];
    const float* eh_b=(const float*)d_in[29];
    const float* nm_w=(const float*)d_in[30];
    const float* nm_b=(const float*)d_in[31];
    const float* nm_g=(const float*)d_in[32];
    const float* nm_bt=(const float*)d_in[33];
    const float* nh_w=(const float*)d_in[34];
    const float* nh_b=(const float*)d_in[35];
    (void)in_sizes; (void)n_in; (void)out_size; (void)ws_size;

    unsigned short* wfrag = (unsigned short*)d_ws;
    float* wsf  = (float*)d_ws;
    float* emb  = wsf + 30720;
    float* qkvb = emb + 122880;
    float* obuf = qkvb + 368640;
    float* outp = (float*)d_out;

    k_wprep   <<<30, 256, 0, stream>>>(conv_w, wfrag);
    k_extract <<<MROWS, 512, 0, stream>>>(edge_data, stem_w, stem_b, wfrag, gn_g, gn_b, emb);
    k_mergeqkv<<<MROWS/8, 256, 0, stream>>>(emb, edge_types, type_emb, em_w, em_b, em_g,
                                            em_bt, a_wqkv, a_bqkv, emb, qkvb);
    // layer 0
    k_attn    <<<NBAT*16, 256, 0, stream>>>(qkvb, obuf);
    k_postattn<<<MROWS/8, 256, 0, stream>>>(obuf, a_wo, a_bo, ln1_g, ln1_b,
                                            ff_w1, ff_b1, ff_w2, ff_b2, ln2_g, ln2_b,
                                            emb, a_wqkv + (size_t)64*192, a_bqkv + 192, qkvb,
                                            (const float*)nullptr, (const float*)nullptr, (float*)nullptr);
    // layer 1 (+ fused edge head)
    k_attn    <<<NBAT*16, 256, 0, stream>>>(qkvb, obuf);
    k_postattn<<<MROWS/8, 256, 0, stream>>>(obuf, a_wo + (size_t)64*64, a_bo + 64,
                                            ln1_g + 64, ln1_b + 64,
                                            ff_w1 + (size_t)64*256, ff_b1 + 256,
                                            ff_w2 + (size_t)256*64, ff_b2 + 64,
                                            ln2_g + 64, ln2_b + 64,
                                            emb, (const float*)nullptr, (const float*)nullptr, qkvb,
                                            eh_w, eh_b, outp);
    k_nodehead<<<28, 256, 0, stream>>>(emb, nm_w, nm_b, nm_g, nm_bt,
                                       nh_w, nh_b, pp, xp, yp, outp);
}

// Round 11
// 248.878 us; speedup vs baseline: 1.0727x; 1.0263x over previous
//
#include <hip/hip_runtime.h>
#include <hip/hip_bf16.h>
#include <math.h>

// Model constants (fixed by shapes)
#define NEDGE 240
#define NBAT  8
#define MROWS 1920   // NBAT*NEDGE
#define NPTS  256
#define CIN   5

typedef __attribute__((ext_vector_type(8))) short  bf16x8;
typedef __attribute__((ext_vector_type(4))) float  f32x4;

// gelu(x) ~= x * sigmoid(x*(c1 + c2*x^2)); sigmoid via exp2 with log2(e) folded
// into the constants. Clamp-free: e->inf => rcp -> 0 => gelu -> 0 (exact limit);
// e->0 => rcp->1 => gelu -> x. 7 VALU ops, 2 transcendental.
__device__ __forceinline__ float gelu_f(float x){
    float t = fmaf(0.10294322f, x*x, 2.30220807f);   // 1.4427*(0.0714, 1.5958)
    float e = __builtin_amdgcn_exp2f(-x*t);
    float r = __builtin_amdgcn_rcpf(e + 1.0f);
    return x*r;
}
__device__ __forceinline__ float wave_sum(float v){
    #pragma unroll
    for (int off=32; off>0; off>>=1) v += __shfl_xor(v, off);
    return v;
}
// wave-uniform broadcast of lane l (compile-time l) -> v_readlane
__device__ __forceinline__ float bcast(float v, int l){
    return __int_as_float(__builtin_amdgcn_readlane(__float_as_int(v), l));
}
__device__ __forceinline__ unsigned short f2bf(float x){   // RNE f32->bf16
    unsigned int u = __float_as_uint(x);
    return (unsigned short)((u + 0x7FFFu + ((u>>16)&1u)) >> 16);
}
__device__ __forceinline__ unsigned pack_bf2(float lo, float hi){
    __hip_bfloat162 t = __float22bfloat162_rn(make_float2(lo, hi));
    union { __hip_bfloat162 b; unsigned u; } cv; cv.b = t;
    return cv.u;
}
// VALU-pipe 16-lane rotate-reduce (DPP row_ror) — keeps stats off the DS pipe
#define DPP_ADD(v, ctrl) \
    { int _t = __builtin_amdgcn_update_dpp(0, __float_as_int(v), (ctrl), 0xF, 0xF, false); \
      (v) += __int_as_float(_t); }
#define ROW16_SUM(v) { DPP_ADD(v,0x121); DPP_ADD(v,0x122); DPP_ADD(v,0x124); DPP_ADD(v,0x128); }
#define SWZ_ADD(v, patt) \
    (v) += __int_as_float(__builtin_amdgcn_ds_swizzle(__float_as_int(v), (patt)))

// ---------------- K0: pre-convert conv weights to bf16 MFMA A-fragments ----
// frag id f = layer*24 + ob*6 + tap*2 + q ; lane m=lane&15 (out ch in o-block),
// k = 32q + 8*(lane>>4) + e (in ch). wf[(f*64+lane)*8+e]
__global__ __launch_bounds__(256) void k_wprep(
    const float* __restrict__ conv_w, unsigned short* __restrict__ wf)
{
    int t = blockIdx.x*256 + threadIdx.x;
    if (t >= 120*64) return;
    int lane = t & 63, f = t >> 6;
    int q = f & 1, tap = (f>>1)%3, ob = (f/6)&3, layer = f/24;
    int o = 16*ob + (lane&15);
    int ibase = 32*q + 8*(lane>>4);
    #pragma unroll
    for (int e=0;e<8;++e){
        int i = ibase + e;
        float w = conv_w[(((size_t)layer*64 + o)*64 + i)*3 + tap];
        wf[(size_t)t*8 + e] = f2bf(w);
    }
}

// ---------------- K1: stem + 5 conv/GN/GELU blocks + pool + merge + qkv ----
// one block (512 thr) per edge; hbf[258][64] bf16, XOR-swizzled 16B chunks.
// Wave w: obgrp=w&1 (o-blocks 2*obgrp,2*obgrp+1), cols 64*(w>>1).
// Fused tail: merge(concat@em_w)+LN+gelu -> emb, then layer-0 qkv -> qkv.
// mpart/e0 reuse gnp (dead after layer 4); qpart reuses hbf (dead after pool).
__global__ __launch_bounds__(512, 2) void k_extract(
    const float* __restrict__ edge_data, const float* __restrict__ stem_w,
    const float* __restrict__ stem_b, const unsigned short* __restrict__ wf,
    const float* __restrict__ gn_g, const float* __restrict__ gn_b,
    const int* __restrict__ edge_types, const float* __restrict__ type_emb,
    const float* __restrict__ em_w, const float* __restrict__ em_b,
    const float* __restrict__ em_g, const float* __restrict__ em_bt,
    const float* __restrict__ wqkv, const float* __restrict__ bqkv,
    float* __restrict__ emb, float* __restrict__ qkv)
{
    __shared__ unsigned short hbf[258*64];    // 33024 B
    __shared__ float redg[8][2][2][2];        // [wave][half][ob][{s,sq}]
    __shared__ float redp[8][4][8];           // [wave][g][ob*4+j]
    __shared__ float gnp[640];                // gn_g (320) ++ gn_b (320); later mpart(512)+e0(64)
    const int m = blockIdx.x, tid = threadIdx.x;
    const int w = tid>>6, lane = tid&63;
    const int g = (lane>>4)&3, l15 = lane&15;
    const int obgrp = w&1, colbase = 64*(w>>1);
    const bf16x8* wfp = (const bf16x8*)wf;

    // A-frags layer0/tap0 (issue early; land during stem): a = ob*2+q
    bf16x8 Ac[4], An[4];
    #pragma unroll
    for (int a=0;a<4;++a)
        Ac[a] = wfp[(size_t)((2*obgrp + (a>>1))*6 + (a&1))*64 + lane];

    for (int i=tid; i<640; i+=512) gnp[i] = (i<320) ? gn_g[i] : gn_b[i-320];

    // ---- loop-invariant LDS addresses
    int i0[2];
    i0[0] = 16*(2*obgrp+0) + 4*g;
    i0[1] = 16*(2*obgrp+1) + 4*g;
    unsigned raddr[3][2];
    {
        unsigned clb = (unsigned)((colbase + l15)*128);
        #pragma unroll
        for (int tap=0;tap<3;++tap)
            #pragma unroll
            for (int q=0;q<2;++q)
                raddr[tap][q] = clb + (unsigned)(((4*q+g) ^ ((l15+tap)&7))<<4);
    }
    unsigned wbase[2];
    #pragma unroll
    for (int ob=0;ob<2;++ob)
        wbase[ob] = (unsigned)((colbase + l15 + 1)*128
                  + (((i0[ob]>>3) ^ ((l15+1)&7))<<4) + ((i0[ob]&7)<<1));

    float h[2][4][4];   // [ob][nbl][j] f32 master

    // ---- stem
    {
        const float* xs = edge_data + (size_t)m*CIN*NPTS;
        float xv[4][5];
        #pragma unroll
        for (int nbl=0;nbl<4;++nbl){
            int n = colbase + 16*nbl + l15;
            #pragma unroll
            for (int c=0;c<5;++c) xv[nbl][c] = xs[c*NPTS + n];
        }
        #pragma unroll
        for (int ob=0;ob<2;++ob){
            #pragma unroll
            for (int j=0;j<4;++j){
                int o = i0[ob] + j;
                float w0=stem_w[o], w1=stem_w[64+o], w2=stem_w[128+o],
                      w3=stem_w[192+o], w4=stem_w[256+o], sb=stem_b[o];
                #pragma unroll
                for (int nbl=0;nbl<4;++nbl)
                    h[ob][nbl][j] = sb + xv[nbl][0]*w0 + xv[nbl][1]*w1
                                  + xv[nbl][2]*w2 + xv[nbl][3]*w3 + xv[nbl][4]*w4;
            }
            #pragma unroll
            for (int nbl=0;nbl<4;++nbl){
                unsigned long long pk = (unsigned long long)pack_bf2(h[ob][nbl][0],h[ob][nbl][1])
                                      | ((unsigned long long)pack_bf2(h[ob][nbl][2],h[ob][nbl][3]) << 32);
                *(unsigned long long*)((char*)hbf + wbase[ob] + 2048*nbl) = pk;
            }
        }
    }
    // zero halo rows n'=0 and n'=257
    if (tid < 32)       ((unsigned int*)hbf)[tid] = 0u;
    else if (tid < 64)  ((unsigned int*)hbf)[257*32 + tid - 32] = 0u;
    __syncthreads();

    // ---- 5 residual conv blocks (MFMA)
    #pragma unroll 1
    for (int layer=0; layer<5; ++layer){
        f32x4 acc[2][4];   // [ob][nbl]
        #pragma unroll
        for (int ob=0;ob<2;++ob)
            #pragma unroll
            for (int nbl=0;nbl<4;++nbl) acc[ob][nbl] = (f32x4){0.f,0.f,0.f,0.f};

        #pragma unroll
        for (int tap=0; tap<3; ++tap){
            // prefetch next tap's (or next layer tap0's) A-frags
            bool doNext = (tap < 2) || (layer < 4);
            int nl = (tap < 2) ? layer : layer+1;
            int nt = (tap < 2) ? tap+1 : 0;
            if (doNext){
                #pragma unroll
                for (int a=0;a<4;++a)
                    An[a] = wfp[(size_t)(nl*24 + (2*obgrp + (a>>1))*6 + nt*2 + (a&1))*64 + lane];
            }
            #pragma unroll
            for (int q=0; q<2; ++q)
            #pragma unroll
            for (int nbl=0; nbl<4; ++nbl){
                bf16x8 Bv = *(const bf16x8*)((const char*)hbf
                              + raddr[tap][q] + (2048*nbl + 128*tap));
                #pragma unroll
                for (int ob=0; ob<2; ++ob)
                    acc[ob][nbl] = __builtin_amdgcn_mfma_f32_16x16x32_bf16(
                                       Ac[ob*2+q], Bv, acc[ob][nbl], 0,0,0);
            }
            if (doNext){
                #pragma unroll
                for (int a=0;a<4;++a) Ac[a] = An[a];
            }
        }

        // GroupNorm stats: group(ob) = 2*(2*obgrp+ob) + (g>>1)
        float s[2], sq[2];
        #pragma unroll
        for (int ob=0;ob<2;++ob){
            float a=0.f, b=0.f;
            #pragma unroll
            for (int nbl=0;nbl<4;++nbl)
                #pragma unroll
                for (int j=0;j<4;++j){ float v=acc[ob][nbl][j]; a+=v; b+=v*v; }
            s[ob]=a; sq[ob]=b;
        }
        #pragma unroll
        for (int ob=0;ob<2;++ob){ ROW16_SUM(s[ob]); ROW16_SUM(sq[ob]); }
        #pragma unroll
        for (int ob=0;ob<2;++ob){ SWZ_ADD(s[ob],0x401F); SWZ_ADD(sq[ob],0x401F); }
        if ((lane&31)==0){
            int half = lane>>5;
            #pragma unroll
            for (int ob=0;ob<2;++ob){
                redg[w][half][ob][0] = s[ob];
                redg[w][half][ob][1] = sq[ob];
            }
        }
        __syncthreads();   // #1: MFMA reads of hbf done; redg published

        int hf = g>>1;
        #pragma unroll
        for (int ob=0;ob<2;++ob){
            float S = redg[obgrp][hf][ob][0] + redg[obgrp+2][hf][ob][0]
                    + redg[obgrp+4][hf][ob][0] + redg[obgrp+6][hf][ob][0];
            float Q = redg[obgrp][hf][ob][1] + redg[obgrp+2][hf][ob][1]
                    + redg[obgrp+4][hf][ob][1] + redg[obgrp+6][hf][ob][1];
            float mu = S*(1.f/2048.f);
            float rstd = rsqrtf(Q*(1.f/2048.f) - mu*mu + 1e-5f);
            // GN folded to 1 FMA per value
            float K1[4], K2[4];
            #pragma unroll
            for (int j=0;j<4;++j){
                float gg = gnp[layer*64 + i0[ob] + j], bb = gnp[320 + layer*64 + i0[ob] + j];
                K1[j] = rstd*gg;
                K2[j] = fmaf(-mu, K1[j], bb);
            }
            #pragma unroll
            for (int nbl=0;nbl<4;++nbl)
                #pragma unroll
                for (int j=0;j<4;++j){
                    float xn = fmaf(acc[ob][nbl][j], K1[j], K2[j]);
                    h[ob][nbl][j] += gelu_f(xn);
                }
        }
        if (layer < 4){
            #pragma unroll
            for (int ob=0;ob<2;++ob)
            #pragma unroll
            for (int nbl=0;nbl<4;++nbl){
                unsigned long long pk = (unsigned long long)pack_bf2(h[ob][nbl][0],h[ob][nbl][1])
                                      | ((unsigned long long)pack_bf2(h[ob][nbl][2],h[ob][nbl][3]) << 32);
                *(unsigned long long*)((char*)hbf + wbase[ob] + 2048*nbl) = pk;
            }
            __syncthreads();   // #2: hbf ready for next layer
        }
    }

    // ---- mean pool over N
    #pragma unroll
    for (int ob=0;ob<2;++ob){
        float p[4];
        #pragma unroll
        for (int j=0;j<4;++j){
            float v = h[ob][0][j]+h[ob][1][j]+h[ob][2][j]+h[ob][3][j];
            ROW16_SUM(v);
            p[j] = v;
        }
        if (l15==0){
            #pragma unroll
            for (int j=0;j<4;++j) redp[w][g][ob*4+j] = p[j];
        }
    }
    __syncthreads();   // redp ready; gnp (gn params) and hbf now dead
    if (tid < 64){
        int og = tid>>5, ob = (tid>>4)&1, gg = (tid>>2)&3, j = tid&3;
        float sum = redp[og][gg][ob*4+j]   + redp[og+2][gg][ob*4+j]
                  + redp[og+4][gg][ob*4+j] + redp[og+6][gg][ob*4+j];
        gnp[512 + tid] = sum * (1.0f/256.0f);   // e0 row (pooled emb)
    }
    __syncthreads();   // e0 ready

    // ---- fused merge: in[128] = concat(e0, temb); wave w covers j in [16w,16w+16)
    {
        int ty = edge_types[m];   // block-uniform
        float mp = 0.f;
        #pragma unroll
        for (int jj=0; jj<16; ++jj){
            int j = w*16 + jj;
            float inj = (w < 4) ? gnp[512 + j] : type_emb[ty*64 + (j - 64)];
            mp = fmaf(inj, em_w[j*64 + lane], mp);
        }
        gnp[w*64 + lane] = mp;    // mpart[8][64]
    }
    __syncthreads();
    if (tid < 64){   // wave 0: combine + LN + gelu
        float x = em_b[tid];
        #pragma unroll
        for (int ww=0; ww<8; ++ww) x += gnp[ww*64 + tid];
        float mu  = wave_sum(x)*(1.f/64.f);
        float d   = x - mu;
        float var = wave_sum(d*d)*(1.f/64.f);
        float e = gelu_f(d*rsqrtf(var+1e-5f)*em_g[tid] + em_bt[tid]);
        emb[(size_t)m*64 + tid] = e;
        gnp[512 + tid] = e;       // merged e row
    }
    __syncthreads();
    // ---- fused layer-0 qkv: waves 0..5, og=w>>1 (q/k/v), jh=w&1 (j-half)
    float* qpart = (float*)hbf;   // 6*64 floats, hbf dead
    if (w < 6){
        int og = w >> 1, jh = w & 1;
        float qp = 0.f;
        #pragma unroll
        for (int jj=0; jj<32; ++jj){
            int j = jh*32 + jj;
            qp = fmaf(gnp[512 + j], wqkv[j*192 + og*64 + lane], qp);
        }
        qpart[w*64 + lane] = qp;
    }
    __syncthreads();
    if (tid < 192){
        int og = tid >> 6, l = tid & 63;
        qkv[(size_t)m*192 + tid] = qpart[(og*2)*64 + l] + qpart[(og*2+1)*64 + l] + bqkv[tid];
    }
}

// ---------------- K3: attention; block = (batch, head, qtile of 64) ---------
__global__ __launch_bounds__(256) void k_attn(
    const float* __restrict__ qkv, float* __restrict__ o)
{
    __shared__ float KsT[16][244], VsT[16][244];
    int blk = blockIdx.x;
    int b  = blk >> 4;
    int h  = (blk >> 2) & 3;
    int qt = blk & 3;
    int tid = threadIdx.x;
    for (int i=tid; i<NEDGE*16; i+=256){
        int r = i>>4, d = i&15;
        size_t base = ((size_t)(b*NEDGE+r))*192 + h*16 + d;
        KsT[d][r] = qkv[base+64];
        VsT[d][r] = qkv[base+128];
    }
    __syncthreads();
    int c = tid & 3, qi = tid >> 2;
    int q = qt*64 + qi;
    bool act = (q < NEDGE);
    float qv[16];
    size_t qb = ((size_t)(b*NEDGE + (act ? q : 0)))*192 + h*16;
    #pragma unroll
    for (int d=0; d<16; ++d) qv[d] = qkv[qb+d];
    float mx = -3e38f, l = 0.f, acc[16];
    #pragma unroll
    for (int d=0; d<16; ++d) acc[d]=0.f;
    for (int k=0; k<60; ++k){
        int key = 60*c + k;
        float s=0.f;
        #pragma unroll
        for (int d=0; d<16; ++d) s += qv[d]*KsT[d][key];
        s *= 0.25f;
        if (s > mx){
            float so = __expf(mx - s);
            l *= so;
            #pragma unroll
            for (int d=0; d<16; ++d) acc[d] *= so;
            mx = s;
        }
        float pp = __expf(s - mx);
        l += pp;
        #pragma unroll
        for (int d=0; d<16; ++d) acc[d] = fmaf(pp, VsT[d][key], acc[d]);
    }
    #pragma unroll
    for (int off=1; off<=2; off<<=1){
        float mo = __shfl_xor(mx, off);
        float lo = __shfl_xor(l,  off);
        float M  = fmaxf(mx, mo);
        float ss = __expf(mx - M);
        float so = __expf(mo - M);
        l = l*ss + lo*so;
        #pragma unroll
        for (int d=0; d<16; ++d)
            acc[d] = acc[d]*ss + __shfl_xor(acc[d], off)*so;
        mx = M;
    }
    if (act && c==0){
        float inv = 1.f/l;
        size_t obase = ((size_t)(b*NEDGE+q))*64 + h*16;
        #pragma unroll
        for (int d=0; d<16; ++d) o[obase+d] = acc[d]*inv;
    }
}

// ---------------- K4: out-proj+LN1+FFN+LN2 (+ qkv | edge head) --------------
// 256 thr, 2 rows/wave: each weight load feeds 2 FMAs; 960 waves for TLP.
__global__ __launch_bounds__(256) void k_postattn(
    const float* __restrict__ o, const float* __restrict__ wo,
    const float* __restrict__ bo, const float* __restrict__ g1,
    const float* __restrict__ b1ln, const float* __restrict__ w1,
    const float* __restrict__ b1, const float* __restrict__ w2,
    const float* __restrict__ b2, const float* __restrict__ g2,
    const float* __restrict__ b2ln, float* __restrict__ emb,
    const float* __restrict__ wqkv, const float* __restrict__ bqkv,
    float* __restrict__ qkv, const float* __restrict__ eh_w,
    const float* __restrict__ eh_b, float* __restrict__ eout)
{
    int m0 = blockIdx.x*8 + (threadIdx.x>>6)*2;
    int ln = threadIdx.x & 63;
    float ov[2], rr[2];
    float bo_ = bo[ln];
    #pragma unroll
    for (int r=0;r<2;++r){ ov[r] = o[(size_t)(m0+r)*64+ln]; rr[r] = bo_; }
    #pragma unroll
    for (int j=0;j<64;++j){
        float w = wo[j*64+ln];
        rr[0] += bcast(ov[0],j)*w; rr[1] += bcast(ov[1],j)*w;
    }
    float g1_=g1[ln], b1_=b1ln[ln];
    float e1[2];
    #pragma unroll
    for (int r=0;r<2;++r){
        float x = emb[(size_t)(m0+r)*64+ln] + rr[r];
        float mu  = wave_sum(x)*(1.f/64.f);
        float d   = x-mu;
        float var = wave_sum(d*d)*(1.f/64.f);
        e1[r] = d*rsqrtf(var+1e-5f)*g1_ + b1_;
    }
    float4 bv4 = *(const float4*)(b1 + ln*4);
    float h[2][4];
    #pragma unroll
    for (int r=0;r<2;++r){ h[r][0]=bv4.x; h[r][1]=bv4.y; h[r][2]=bv4.z; h[r][3]=bv4.w; }
    #pragma unroll
    for (int j=0;j<64;++j){
        float4 wv = *(const float4*)(w1 + j*256 + ln*4);
        #pragma unroll
        for (int r=0;r<2;++r){
            float ej = bcast(e1[r],j);
            h[r][0] += ej*wv.x; h[r][1] += ej*wv.y;
            h[r][2] += ej*wv.z; h[r][3] += ej*wv.w;
        }
    }
    #pragma unroll
    for (int r=0;r<2;++r)
        #pragma unroll
        for (int u=0;u<4;++u) h[r][u] = gelu_f(h[r][u]);
    float f[2];
    float b2_ = b2[ln];
    f[0]=b2_; f[1]=b2_;
    #pragma unroll
    for (int j=0;j<64;++j){
        #pragma unroll
        for (int u=0;u<4;++u){
            float w = w2[(j*4+u)*64+ln];
            f[0] += bcast(h[0][u],j)*w; f[1] += bcast(h[1][u],j)*w;
        }
    }
    float g2_=g2[ln], b2l_=b2ln[ln];
    float e2[2];
    #pragma unroll
    for (int r=0;r<2;++r){
        float x2 = e1[r] + f[r];
        float mu2  = wave_sum(x2)*(1.f/64.f);
        float d2   = x2-mu2;
        float var2 = wave_sum(d2*d2)*(1.f/64.f);
        e2[r] = d2*rsqrtf(var2+1e-5f)*g2_ + b2l_;
        emb[(size_t)(m0+r)*64+ln] = e2[r];
    }
    if (wqkv){
        float q[2], k[2], vv[2];
        float bq = bqkv[ln], bk = bqkv[64+ln], bv = bqkv[128+ln];
        #pragma unroll
        for (int r=0;r<2;++r){ q[r]=bq; k[r]=bk; vv[r]=bv; }
        #pragma unroll
        for (int j=0;j<64;++j){
            float wq = wqkv[j*192+ln], wk = wqkv[j*192+64+ln], wv = wqkv[j*192+128+ln];
            #pragma unroll
            for (int r=0;r<2;++r){
                float ej = bcast(e2[r],j);
                q[r] += ej*wq; k[r] += ej*wk; vv[r] += ej*wv;
            }
        }
        #pragma unroll
        for (int r=0;r<2;++r){
            size_t base = (size_t)(m0+r)*192;
            qkv[base+ln]=q[r]; qkv[base+64+ln]=k[r]; qkv[base+128+ln]=vv[r];
        }
    }
    if (eh_w){   // fused edge head (layer 1)
        float w0 = eh_w[ln*2+0], w1e = eh_w[ln*2+1];
        #pragma unroll
        for (int r=0;r<2;++r){
            float p0 = wave_sum(e2[r]*w0);
            float p1 = wave_sum(e2[r]*w1e);
            if (ln==0){
                eout[(size_t)(m0+r)*2+0] = p0 + eh_b[0];
                eout[(size_t)(m0+r)*2+1] = p1 + eh_b[1];
            }
        }
    }
}

// ---------------- K5: node head ---------------------------------------------
__global__ __launch_bounds__(256) void k_nodehead(
    const float* __restrict__ emb, const float* __restrict__ nm_w,
    const float* __restrict__ nm_b, const float* __restrict__ nm_g,
    const float* __restrict__ nm_bt, const float* __restrict__ nh_w,
    const float* __restrict__ nh_b, const int* __restrict__ pp,
    const int* __restrict__ xp, const int* __restrict__ yp,
    float* __restrict__ out)
{
    int wid = blockIdx.x*4 + (threadIdx.x>>6);
    int ln  = threadIdx.x & 63;
    int p = pp[0], xi = xp[0], yi = yp[0];
    int nu = p-2;
    if (wid >= NBAT*nu) return;
    int b = wid / nu, r = wid % nu;
    int u=-1, cnt=0;
    for (int i=0;i<p;++i){ if (i!=xi && i!=yi){ if (cnt==r){u=i;break;} ++cnt; } }
    #define EIDX(a,v) ((a)*(p-1) + (v) - (((v)>(a))?1:0))
    int iux = EIDX(u,xi), iuy = EIDX(u,yi), ixu = EIDX(xi,u), iyu = EIDX(yi,u);
    float g0 = emb[((size_t)(b*NEDGE+iux))*64+ln];
    float g1 = emb[((size_t)(b*NEDGE+iuy))*64+ln];
    float g2 = emb[((size_t)(b*NEDGE+ixu))*64+ln];
    float g3 = emb[((size_t)(b*NEDGE+iyu))*64+ln];
    float v = nm_b[ln];
    #pragma unroll
    for (int j=0;j<64;++j) v += bcast(g0,j)*nm_w[j*64+ln];
    #pragma unroll
    for (int j=0;j<64;++j) v += bcast(g1,j)*nm_w[(64+j)*64+ln];
    #pragma unroll
    for (int j=0;j<64;++j) v += bcast(g2,j)*nm_w[(128+j)*64+ln];
    #pragma unroll
    for (int j=0;j<64;++j) v += bcast(g3,j)*nm_w[(192+j)*64+ln];
    float mu  = wave_sum(v)*(1.f/64.f);
    float d   = v-mu;
    float var = wave_sum(d*d)*(1.f/64.f);
    float node = gelu_f(d*rsqrtf(var+1e-5f)*nm_g[ln] + nm_bt[ln]);
    float pl[8];
    #pragma unroll
    for (int c=0;c<8;++c) pl[c] = node*nh_w[ln*8+c];
    #pragma unroll
    for (int off=32; off>0; off>>=1)
        #pragma unroll
        for (int c=0;c<8;++c) pl[c] += __shfl_xor(pl[c], off);
    if (ln==0){
        #pragma unroll
        for (int c=0;c<8;++c) out[MROWS*2 + ((size_t)wid)*8 + c] = pl[c] + nh_b[c];
    }
}

extern "C" void kernel_launch(void* const* d_in, const int* in_sizes, int n_in,
                              void* d_out, int out_size, void* d_ws, size_t ws_size,
                              hipStream_t stream)
{
    const float* edge_data = (const float*)d_in[0];
    const int*   edge_types= (const int*)d_in[1];
    const int* pp = (const int*)d_in[3];
    const int* xp = (const int*)d_in[4];
    const int* yp = (const int*)d_in[5];
    const float* stem_w=(const float*)d_in[6];
    const float* stem_b=(const float*)d_in[7];
    const float* conv_w=(const float*)d_in[8];
    const float* gn_g=(const float*)d_in[9];
    const float* gn_b=(const float*)d_in[10];
    const float* type_emb=(const float*)d_in[11];
    const float* em_w=(const float*)d_in[12];
    const float* em_b=(const float*)d_in[13];
    const float* em_g=(const float*)d_in[14];
    const float* em_bt=(const float*)d_in[15];
    const float* a_wqkv=(const float*)d_in[16];
    const float* a_bqkv=(const float*)d_in[17];
    const float* a_wo=(const float*)d_in[18];
    const float* a_bo=(const float*)d_in[19];
    const float* ln1_g=(const float*)d_in[20];
    const float* ln1_b=(const float*)d_in[21];
    const float* ff_w1=(const float*)d_in[22];
    const float* ff_b1=(const float*)d_in[23];
    const float* ff_w2=(const float*)d_in[24];
    const float* ff_b2=(const float*)d_in[25];
    const float* ln2_g=(const float*)d_in[26];
    const float* ln2_b=(const float*)d_in[27];
    const float* eh_w=(const float*)d_in[28];
    const float* eh_b=(const float*)d_in[29];
    const float* nm_w=(const float*)d_in[30];
    const float* nm_b=(const float*)d_in[31];
    const float* nm_g=(const float*)d_in[32];
    const float* nm_bt=(const float*)d_in[33];
    const float* nh_w=(const float*)d_in[34];
    const float* nh_b=(const float*)d_in[35];
    (void)in_sizes; (void)n_in; (void)out_size; (void)ws_size;

    unsigned short* wfrag = (unsigned short*)d_ws;
    float* wsf  = (float*)d_ws;
    float* emb  = wsf + 30720;
    float* qkvb = emb + 122880;
    float* obuf = qkvb + 368640;
    float* outp = (float*)d_out;

    k_wprep   <<<30, 256, 0, stream>>>(conv_w, wfrag);
    k_extract <<<MROWS, 512, 0, stream>>>(edge_data, stem_w, stem_b, wfrag, gn_g, gn_b,
                                          edge_types, type_emb, em_w, em_b, em_g, em_bt,
                                          a_wqkv, a_bqkv, emb, qkvb);
    // layer 0
    k_attn    <<<NBAT*16, 256, 0, stream>>>(qkvb, obuf);
    k_postattn<<<MROWS/8, 256, 0, stream>>>(obuf, a_wo, a_bo, ln1_g, ln1_b,
                                            ff_w1, ff_b1, ff_w2, ff_b2, ln2_g, ln2_b,
                                            emb, a_wqkv + (size_t)64*192, a_bqkv + 192, qkvb,
                                            (const float*)nullptr, (const float*)nullptr, (float*)nullptr);
    // layer 1 (+ fused edge head)
    k_attn    <<<NBAT*16, 256, 0, stream>>>(qkvb, obuf);
    k_postattn<<<MROWS/8, 256, 0, stream>>>(obuf, a_wo + (size_t)64*64, a_bo + 64,
                                            ln1_g + 64, ln1_b + 64,
                                            ff_w1 + (size_t)64*256, ff_b1 + 256,
                                            ff_w2 + (size_t)256*64, ff_b2 + 64,
                                            ln2_g + 64, ln2_b + 64,
                                            emb, (const float*)nullptr, (const float*)nullptr, qkvb,
                                            eh_w, eh_b, outp);
    k_nodehead<<<28, 256, 0, stream>>>(emb, nm_w, nm_b, nm_g, nm_bt,
                                       nh_w, nh_b, pp, xp, yp, outp);
}